// Round 6
// baseline (159.857 us; speedup 1.0000x reference)
//
#include <hip/hip_runtime.h>

#define N_NODES 8192
#define HIDDEN 256
#define OUT_DIM 16
#define PBLK 512               // pool-partial blocks; P[PBLK][HIDDEN]
#define NPB (N_NODES / PBLK)   // 16 nodes per pool block
#define ELDS 512               // LDS edge stage per scan block (expect ~32)
#define EMAXG (1 << 20)        // global edge-list capacity (expect ~131K)
#define G_ROWS 16              // rows per block, slow-path GEMM

// ---------------- K0: zero deg/sacc/qacc/ecnt; v = relu(W1)@W2; flag --------
__global__ void k_init(const float* __restrict__ W1, const float* __restrict__ b1,
                       const float* __restrict__ W2, int* __restrict__ deg,
                       float* __restrict__ sacc, float* __restrict__ qacc,
                       int* __restrict__ ecnt, float* __restrict__ v,
                       int* __restrict__ flag) {
    const int t = threadIdx.x;         // 256
    const int bid = blockIdx.x;        // 33
    if (bid < 32) {
        const int idx = bid * 256 + t;
        deg[idx] = 0; sacc[idx] = 0.0f; qacc[idx] = 0.0f;
        return;
    }
    // block 32: v, flag, ecnt (independent of adj)
    float acc = 0.0f;
    for (int k = 0; k < HIDDEN; ++k)
        acc += fmaxf(W1[k], 0.0f) * W2[(size_t)k * HIDDEN + t];   // coalesced
    v[t] = acc;
    __shared__ int nz;
    if (t == 0) { nz = 0; *ecnt = 0; }
    __syncthreads();
    if (b1[t] != 0.0f) atomicOr(&nz, 1);
    __syncthreads();
    if (t == 0) *flag = (nz == 0) ? 1 : 0;
}

// ---------------- K1: triangle scan -> flat global edge list ----------------
// Per-hit: LDS append only. Per-block: ONE return-atomic reserves a slice of
// elist; coalesced burst store. (R4/R5 lesson: no per-edge return-dependent
// global atomics anywhere.)
__device__ __forceinline__ void scan_row_tri(const float* __restrict__ adj, int i,
                                             int t, int* ecl, int* el) {
    const uint4* row4 = (const uint4*)(adj + (size_t)i * N_NODES);
    const int k0 = (i + 1) >> 2;       // first uint4 that can contain cols > i
    for (int k = k0 + t; k < N_NODES / 4; k += 256) {
        uint4 vv = row4[k];
        if (vv.x | vv.y | vv.z | vv.w) {   // entries are exactly 0.0f or 1.0f
            int base = k * 4;
            if (vv.x && base + 0 > i) { int p = atomicAdd(ecl, 1); if (p < ELDS) el[p] = (i << 13) | (base + 0); }
            if (vv.y && base + 1 > i) { int p = atomicAdd(ecl, 1); if (p < ELDS) el[p] = (i << 13) | (base + 1); }
            if (vv.z && base + 2 > i) { int p = atomicAdd(ecl, 1); if (p < ELDS) el[p] = (i << 13) | (base + 2); }
            if (vv.w && base + 3 > i) { int p = atomicAdd(ecl, 1); if (p < ELDS) el[p] = (i << 13) | (base + 3); }
        }
    }
}

__global__ void k_scan(const float* __restrict__ adj, int* __restrict__ ecnt,
                       int* __restrict__ elist) {
    const int t = threadIdx.x;             // 256
    const int ia = blockIdx.x;             // 0..4095
    const int ib = N_NODES - 1 - ia;       // pair rows: combined ~8191 elements
    __shared__ int ecl;
    __shared__ int el[ELDS];
    __shared__ int base_s;
    if (t == 0) ecl = 0;
    __syncthreads();
    scan_row_tri(adj, ia, t, &ecl, el);
    scan_row_tri(adj, ib, t, &ecl, el);
    __syncthreads();
    int n = ecl; if (n > ELDS) n = ELDS;
    if (t == 0) base_s = atomicAdd(ecnt, n);    // one return-atomic per block
    __syncthreads();
    const int base = base_s;
    for (int e = t; e < n; e += 256) {          // coalesced burst
        const int idx = base + e;
        if (idx < EMAXG) elist[idx] = el[e];
    }
}

// ---------------- K2: deg scatter (no-return int atomics) -------------------
__global__ void k_deg(const int* __restrict__ ecnt, const int* __restrict__ elist,
                      int* __restrict__ deg) {
    int ne = *ecnt; if (ne > EMAXG) ne = EMAXG;
    const int stride = gridDim.x * blockDim.x;
    for (int e = blockIdx.x * blockDim.x + threadIdx.x; e < ne; e += stride) {
        const int u = elist[e];
        atomicAdd(&deg[u >> 13], 1);            // no return use: fire-and-forget
        atomicAdd(&deg[u & (N_NODES - 1)], 1);
    }
}

// ---------------- K3: s scatter: sacc[i]+=dj, sacc[j]+=di -------------------
__global__ void k_sscat(const int* __restrict__ ecnt, const int* __restrict__ elist,
                        const int* __restrict__ deg, float* __restrict__ sacc) {
    int ne = *ecnt; if (ne > EMAXG) ne = EMAXG;
    const int stride = gridDim.x * blockDim.x;
    for (int e = blockIdx.x * blockDim.x + threadIdx.x; e < ne; e += stride) {
        const int u = elist[e];
        const int i = u >> 13, j = u & (N_NODES - 1);
        const float di = rsqrtf((float)(deg[i] + 1));
        const float dj = rsqrtf((float)(deg[j] + 1));
        atomicAdd(&sacc[i], dj);
        atomicAdd(&sacc[j], di);
    }
}

// ---------------- K4: q scatter: qacc[i]+=tt_j, qacc[j]+=tt_i ---------------
// tt_x = dx*s_x, s_x = dx*(dx + sacc_x) — recomputed inline (sacc complete).
__global__ void k_qscat(const int* __restrict__ ecnt, const int* __restrict__ elist,
                        const int* __restrict__ deg, const float* __restrict__ sacc,
                        float* __restrict__ qacc) {
    int ne = *ecnt; if (ne > EMAXG) ne = EMAXG;
    const int stride = gridDim.x * blockDim.x;
    for (int e = blockIdx.x * blockDim.x + threadIdx.x; e < ne; e += stride) {
        const int u = elist[e];
        const int i = u >> 13, j = u & (N_NODES - 1);
        const float di = rsqrtf((float)(deg[i] + 1));
        const float dj = rsqrtf((float)(deg[j] + 1));
        const float tti = di * di * (di + sacc[i]);
        const float ttj = dj * dj * (dj + sacc[j]);
        atomicAdd(&qacc[i], ttj);
        atomicAdd(&qacc[j], tti);
    }
}

// ---------------- SLOW K5: g = relu(s (x) W1 + b1) @ W2  (predicated) -------
__global__ void k_gemm(const int* __restrict__ deg, const float* __restrict__ sacc,
                       const float* __restrict__ W1, const float* __restrict__ b1,
                       const float* __restrict__ W2, const int* __restrict__ flag,
                       float* __restrict__ g) {
    if (*flag) return;                         // fast path active: no-op
    const int t = threadIdx.x;
    const int row0 = blockIdx.x * G_ROWS;
    __shared__ float hT[HIDDEN][G_ROWS];
    const float w1 = W1[t];
    const float bb = b1[t];
    for (int r = 0; r < G_ROWS; ++r) {
        const int i = row0 + r;
        const float di = rsqrtf((float)(deg[i] + 1));
        const float si = di * (di + sacc[i]);
        hT[t][r] = fmaxf(si * w1 + bb, 0.0f);
    }
    __syncthreads();
    float acc[G_ROWS];
    #pragma unroll
    for (int r = 0; r < G_ROWS; ++r) acc[r] = 0.0f;
    for (int k = 0; k < HIDDEN; ++k) {
        const float w2 = W2[(size_t)k * HIDDEN + t];
        const float4 h0 = *(const float4*)&hT[k][0];
        const float4 h1 = *(const float4*)&hT[k][4];
        const float4 h2 = *(const float4*)&hT[k][8];
        const float4 h3 = *(const float4*)&hT[k][12];
        acc[0]  += h0.x * w2;  acc[1]  += h0.y * w2;  acc[2]  += h0.z * w2;  acc[3]  += h0.w * w2;
        acc[4]  += h1.x * w2;  acc[5]  += h1.y * w2;  acc[6]  += h1.z * w2;  acc[7]  += h1.w * w2;
        acc[8]  += h2.x * w2;  acc[9]  += h2.y * w2;  acc[10] += h2.z * w2;  acc[11] += h2.w * w2;
        acc[12] += h3.x * w2;  acc[13] += h3.y * w2;  acc[14] += h3.z * w2;  acc[15] += h3.w * w2;
    }
    #pragma unroll
    for (int r = 0; r < G_ROWS; ++r)
        g[(size_t)(row0 + r) * HIDDEN + t] = acc[r];
}

// ---------------- K6: pool partials -> P[PBLK][HIDDEN] ----------------------
// FAST: node-local q = di*(di*s + qacc); pp = sum relu(q*v + b2). No gathers.
// SLOW: dense rescan of each node's adj row, gather g rows (insurance path).
__global__ void k_pool(const float* __restrict__ adj, const int* __restrict__ deg,
                       const float* __restrict__ sacc, const float* __restrict__ qacc,
                       const float* __restrict__ g, const float* __restrict__ v,
                       const float* __restrict__ b2, const int* __restrict__ flag,
                       float* __restrict__ P) {
    const int t = threadIdx.x;
    const int bid = blockIdx.x;            // 512
    if (*flag) {
        __shared__ float qsh[NPB];
        if (t < NPB) {
            const int i = bid * NPB + t;
            const float di = rsqrtf((float)(deg[i] + 1));
            const float si = di * (di + sacc[i]);
            qsh[t] = di * (di * si + qacc[i]);
        }
        __syncthreads();
        const float vc = v[t], bc = b2[t];
        float pp = 0.0f;
        #pragma unroll
        for (int n = 0; n < NPB; ++n) pp += fmaxf(qsh[n] * vc + bc, 0.0f);
        P[(size_t)bid * HIDDEN + t] = pp;
    } else {
        __shared__ int hl[ELDS];
        __shared__ int hcnt;
        const float bc = b2[t];
        float pool = 0.0f;
        for (int n = 0; n < NPB; ++n) {
            const int i = bid * NPB + n;
            if (t == 0) hcnt = 0;
            __syncthreads();
            const uint4* row4 = (const uint4*)(adj + (size_t)i * N_NODES);
            for (int k = t; k < N_NODES / 4; k += 256) {
                uint4 vv = row4[k];
                if (vv.x | vv.y | vv.z | vv.w) {
                    int base = k * 4;
                    if (vv.x && base + 0 != i) { int p = atomicAdd(&hcnt, 1); if (p < ELDS) hl[p] = base + 0; }
                    if (vv.y && base + 1 != i) { int p = atomicAdd(&hcnt, 1); if (p < ELDS) hl[p] = base + 1; }
                    if (vv.z && base + 2 != i) { int p = atomicAdd(&hcnt, 1); if (p < ELDS) hl[p] = base + 2; }
                    if (vv.w && base + 3 != i) { int p = atomicAdd(&hcnt, 1); if (p < ELDS) hl[p] = base + 3; }
                }
            }
            __syncthreads();
            const float di = rsqrtf((float)(deg[i] + 1));
            float acc = di * g[(size_t)i * HIDDEN + t];
            int nh = hcnt; if (nh > ELDS) nh = ELDS;
            for (int e = 0; e < nh; ++e) {
                const int j = hl[e];
                acc += rsqrtf((float)(deg[j] + 1)) * g[(size_t)j * HIDDEN + t];
            }
            pool += fmaxf(di * acc + bc, 0.0f);
            __syncthreads();
        }
        P[(size_t)bid * HIDDEN + t] = pool;
    }
}

// ---------------- K7: pooled = sum P; out = pooled @ Wfc + bfc --------------
__global__ void k_finish(const float* __restrict__ P, const float* __restrict__ Wfc,
                         const float* __restrict__ bfc, float* __restrict__ out) {
    const int t = threadIdx.x;      // 256
    float a0 = 0.f, a1 = 0.f, a2 = 0.f, a3 = 0.f;
    #pragma unroll 8
    for (int r = 0; r < PBLK; r += 4) {
        a0 += P[(size_t)(r + 0) * HIDDEN + t];
        a1 += P[(size_t)(r + 1) * HIDDEN + t];
        a2 += P[(size_t)(r + 2) * HIDDEN + t];
        a3 += P[(size_t)(r + 3) * HIDDEN + t];
    }
    __shared__ float pooled[HIDDEN];
    pooled[t] = (a0 + a1) + (a2 + a3);
    __syncthreads();
    const int o = t & 15, kg = t >> 4;
    float pr = 0.0f;
    for (int k = kg; k < HIDDEN; k += 16) pr += pooled[k] * Wfc[k * OUT_DIM + o];
    __shared__ float red[256];
    red[t] = pr;
    __syncthreads();
    if (t < OUT_DIM) {
        float sum = bfc[t];
        #pragma unroll
        for (int gg = 0; gg < 16; ++gg) sum += red[gg * 16 + t];
        out[t] = sum;
    }
}

extern "C" void kernel_launch(void* const* d_in, const int* in_sizes, int n_in,
                              void* d_out, int out_size, void* d_ws, size_t ws_size,
                              hipStream_t stream) {
    const float* adj = (const float*)d_in[0];
    const float* W1  = (const float*)d_in[1];
    const float* b1  = (const float*)d_in[2];
    const float* W2  = (const float*)d_in[3];
    const float* b2  = (const float*)d_in[4];
    const float* Wfc = (const float*)d_in[5];
    const float* bfc = (const float*)d_in[6];
    float* out = (float*)d_out;

    // workspace layout (16 MiB used)
    char* ws = (char*)d_ws;
    int*   deg  = (int*)  (ws + 0);                 // 32 KB
    float* sacc = (float*)(ws + (32 << 10));        // 32 KB
    float* qacc = (float*)(ws + (64 << 10));        // 32 KB
    float* v    = (float*)(ws + (96 << 10));        // 1 KB
    int*   flag = (int*)  (ws + (100 << 10));       // 4 B
    int*   ecnt = (int*)  (ws + (104 << 10));       // 4 B
    float* P    = (float*)(ws + (256 << 10));       // 512 KB (512 x 256)
    int*   elist= (int*)  (ws + (1 << 20));         // 4 MB (EMAXG entries)
    float* g    = (float*)(ws + (8 << 20));         // 8 MB (slow path only)

    k_init  <<<33, 256, 0, stream>>>(W1, b1, W2, deg, sacc, qacc, ecnt, v, flag);
    k_scan  <<<N_NODES / 2, 256, 0, stream>>>(adj, ecnt, elist);
    k_deg   <<<256, 256, 0, stream>>>(ecnt, elist, deg);
    k_sscat <<<256, 256, 0, stream>>>(ecnt, elist, deg, sacc);
    k_qscat <<<256, 256, 0, stream>>>(ecnt, elist, deg, sacc, qacc);
    k_gemm  <<<N_NODES / G_ROWS, 256, 0, stream>>>(deg, sacc, W1, b1, W2, flag, g);
    k_pool  <<<PBLK, 256, 0, stream>>>(adj, deg, sacc, qacc, g, v, b2, flag, P);
    k_finish<<<1, 256, 0, stream>>>(P, Wfc, bfc, out);
}

// Round 7
// 86.413 us; speedup vs baseline: 1.8499x; 1.8499x over previous
//
#include <hip/hip_runtime.h>

#define N_NODES 8192
#define HIDDEN 256
#define OUT_DIM 16
#define CAP 128                 // max neighbors stored; binomial max deg ~60 << 128
#define G_ROWS 16               // rows per block in the slow dense GEMM
#define POOL_BLK 64             // pool-partial blocks; P[POOL_BLK][HIDDEN] = 64 KB
#define NPPB (N_NODES / POOL_BLK)   // 128 nodes per pool block

// ---------------- K1: dense row scan -> CSR (LDS counter, plain stores) -----
// R2-proven structure: each block owns one row; the ONLY atomic is in LDS.
// Extra 16 blocks (bid >= N_NODES) compute v = relu(W1)@W2 and flag=(b1==0),
// hidden under the HBM-bound scan.
__global__ void k_scan(const float* __restrict__ adj, const float* __restrict__ W1,
                       const float* __restrict__ b1, const float* __restrict__ W2,
                       int* __restrict__ cnt, int* __restrict__ nbr,
                       float* __restrict__ v, int* __restrict__ flag) {
    const int t = threadIdx.x;         // 256
    const int bid = blockIdx.x;        // 8192 + 16

    if (bid >= N_NODES) {              // ---- v / flag blocks ----
        const int bv = bid - N_NODES;  // 0..15
        __shared__ float sm[256];
        __shared__ int nz;
        if (t == 0) nz = 0;
        __syncthreads();
        if (bv == 0 && b1[t] != 0.0f) atomicOr(&nz, 1);
        const int kg = t >> 4, cl = t & 15;
        const int c = bv * 16 + cl;
        float partial = 0.0f;
        for (int k = kg; k < HIDDEN; k += 16)
            partial += fmaxf(W1[k], 0.0f) * W2[(size_t)k * HIDDEN + c];
        sm[t] = partial;
        __syncthreads();
        if (bv == 0 && t == 0) *flag = (nz == 0) ? 1 : 0;
        if (t < 16) {
            float acc = 0.0f;
            #pragma unroll
            for (int gg = 0; gg < 16; ++gg) acc += sm[gg * 16 + t];
            v[bv * 16 + t] = acc;
        }
        return;
    }

    // ---- row-builder blocks ----
    const int i = bid;
    __shared__ int scnt;
    if (t == 0) scnt = 0;
    __syncthreads();
    const uint4* row = (const uint4*)(adj + (size_t)i * N_NODES);
    #pragma unroll
    for (int c8 = 0; c8 < N_NODES / 4 / 256; ++c8) {   // 8 iterations
        uint4 vv = row[c8 * 256 + t];
        int base = (c8 * 256 + t) * 4;
        if (vv.x | vv.y | vv.z | vv.w) {   // adj entries are exactly 0.0f or 1.0f
            if (vv.x && base + 0 != i) { int p = atomicAdd(&scnt, 1); if (p < CAP) nbr[(size_t)i * CAP + p] = base + 0; }
            if (vv.y && base + 1 != i) { int p = atomicAdd(&scnt, 1); if (p < CAP) nbr[(size_t)i * CAP + p] = base + 1; }
            if (vv.z && base + 2 != i) { int p = atomicAdd(&scnt, 1); if (p < CAP) nbr[(size_t)i * CAP + p] = base + 2; }
            if (vv.w && base + 3 != i) { int p = atomicAdd(&scnt, 1); if (p < CAP) nbr[(size_t)i * CAP + p] = base + 3; }
        }
    }
    __syncthreads();
    if (t == 0) {
        int c = scnt < CAP ? scnt : CAP;
        cnt[i] = c;
    }
}

// ---------------- K2: s_i = di*(di + sum dinv_j); tt_i = di*s_i -------------
__global__ void k_srow(const int* __restrict__ cnt, const int* __restrict__ nbr,
                       float* __restrict__ s, float* __restrict__ tt) {
    const int w = threadIdx.x >> 6;    // wave 0..3, one node per wave
    const int lane = threadIdx.x & 63;
    const int i = blockIdx.x * 4 + w;
    const int c = cnt[i];
    const float di = rsqrtf((float)(c + 1));   // +1 self loop
    float p = 0.0f;
    for (int k = lane; k < c; k += 64)
        p += rsqrtf((float)(cnt[nbr[(size_t)i * CAP + k]] + 1));
    #pragma unroll
    for (int off = 32; off > 0; off >>= 1) p += __shfl_down(p, off);
    if (lane == 0) {
        const float si = di * (di + p);
        s[i] = si; tt[i] = di * si;
    }
}

// ---------------- SLOW K3: g = relu(s (x) W1 + b1) @ W2  (predicated) -------
__global__ void k_gemm(const float* __restrict__ s, const float* __restrict__ W1,
                       const float* __restrict__ b1, const float* __restrict__ W2,
                       const int* __restrict__ flag, float* __restrict__ g) {
    if (*flag) return;                         // fast path active: no-op
    const int t = threadIdx.x;
    const int row0 = blockIdx.x * G_ROWS;
    __shared__ float hT[HIDDEN][G_ROWS];
    const float w1 = W1[t];
    const float bb = b1[t];
    for (int r = 0; r < G_ROWS; ++r)
        hT[t][r] = fmaxf(s[row0 + r] * w1 + bb, 0.0f);
    __syncthreads();
    float acc[G_ROWS];
    #pragma unroll
    for (int r = 0; r < G_ROWS; ++r) acc[r] = 0.0f;
    for (int k = 0; k < HIDDEN; ++k) {
        const float w2 = W2[(size_t)k * HIDDEN + t];
        const float4 h0 = *(const float4*)&hT[k][0];
        const float4 h1 = *(const float4*)&hT[k][4];
        const float4 h2 = *(const float4*)&hT[k][8];
        const float4 h3 = *(const float4*)&hT[k][12];
        acc[0]  += h0.x * w2;  acc[1]  += h0.y * w2;  acc[2]  += h0.z * w2;  acc[3]  += h0.w * w2;
        acc[4]  += h1.x * w2;  acc[5]  += h1.y * w2;  acc[6]  += h1.z * w2;  acc[7]  += h1.w * w2;
        acc[8]  += h2.x * w2;  acc[9]  += h2.y * w2;  acc[10] += h2.z * w2;  acc[11] += h2.w * w2;
        acc[12] += h3.x * w2;  acc[13] += h3.y * w2;  acc[14] += h3.z * w2;  acc[15] += h3.w * w2;
    }
    #pragma unroll
    for (int r = 0; r < G_ROWS; ++r)
        g[(size_t)(row0 + r) * HIDDEN + t] = acc[r];
}

// ---------------- K4: pool partials -> P[POOL_BLK][HIDDEN] ------------------
// FAST: q_i = di*(di*s_i + sum tt_j) per node-wave, pool relu(q*v+b2).
// SLOW: CSR gather of g rows (insurance; never taken when b1==0).
// Both branches write every P row -> no zeroing pass needed.
__global__ void k_pool(const int* __restrict__ cnt, const int* __restrict__ nbr,
                       const float* __restrict__ s, const float* __restrict__ tt,
                       const float* __restrict__ g, const float* __restrict__ v,
                       const float* __restrict__ b2, const int* __restrict__ flag,
                       float* __restrict__ P) {
    const int t = threadIdx.x;
    const int bid = blockIdx.x;            // 64
    if (*flag) {
        __shared__ float qsh[NPPB];
        const int w = t >> 6, lane = t & 63;
        for (int r = 0; r < NPPB / 4; ++r) {       // 32 rounds, 1 node/wave
            const int i = bid * NPPB + r * 4 + w;
            const int c = cnt[i];
            const float di = rsqrtf((float)(c + 1));
            float p = 0.0f;
            for (int k = lane; k < c; k += 64) p += tt[nbr[(size_t)i * CAP + k]];
            #pragma unroll
            for (int off = 32; off > 0; off >>= 1) p += __shfl_down(p, off);
            if (lane == 0) qsh[r * 4 + w] = di * (di * s[i] + p);
        }
        __syncthreads();
        const float vc = v[t], bc = b2[t];
        float pp = 0.0f;
        #pragma unroll 8
        for (int n = 0; n < NPPB; ++n) pp += fmaxf(qsh[n] * vc + bc, 0.0f);
        P[(size_t)bid * HIDDEN + t] = pp;
    } else {
        const float bc = b2[t];
        float pool = 0.0f;
        for (int n = 0; n < NPPB; ++n) {
            const int i = bid * NPPB + n;
            const int c = cnt[i];
            const float di = rsqrtf((float)(c + 1));
            float val = di * g[(size_t)i * HIDDEN + t];
            const int* nb = nbr + (size_t)i * CAP;
            for (int k = 0; k < c; ++k) {
                const int j = nb[k];
                val += rsqrtf((float)(cnt[j] + 1)) * g[(size_t)j * HIDDEN + t];
            }
            pool += fmaxf(di * val + bc, 0.0f);
        }
        P[(size_t)bid * HIDDEN + t] = pool;
    }
}

// ---------------- K5: pooled = sum P (64 KB); out = pooled @ Wfc + bfc ------
__global__ void k_finish(const float* __restrict__ P, const float* __restrict__ Wfc,
                         const float* __restrict__ bfc, float* __restrict__ out) {
    const int t = threadIdx.x;      // 256
    float a0 = 0.f, a1 = 0.f, a2 = 0.f, a3 = 0.f;
    #pragma unroll
    for (int r = 0; r < POOL_BLK; r += 4) {
        a0 += P[(size_t)(r + 0) * HIDDEN + t];
        a1 += P[(size_t)(r + 1) * HIDDEN + t];
        a2 += P[(size_t)(r + 2) * HIDDEN + t];
        a3 += P[(size_t)(r + 3) * HIDDEN + t];
    }
    __shared__ float pooled[HIDDEN];
    pooled[t] = (a0 + a1) + (a2 + a3);
    __syncthreads();
    const int o = t & 15, kg = t >> 4;
    float pr = 0.0f;
    for (int k = kg; k < HIDDEN; k += 16) pr += pooled[k] * Wfc[k * OUT_DIM + o];
    __shared__ float red[256];
    red[t] = pr;
    __syncthreads();
    if (t < OUT_DIM) {
        float sum = bfc[t];
        #pragma unroll
        for (int gg = 0; gg < 16; ++gg) sum += red[gg * 16 + t];
        out[t] = sum;
    }
}

extern "C" void kernel_launch(void* const* d_in, const int* in_sizes, int n_in,
                              void* d_out, int out_size, void* d_ws, size_t ws_size,
                              hipStream_t stream) {
    const float* adj = (const float*)d_in[0];
    const float* W1  = (const float*)d_in[1];
    const float* b1  = (const float*)d_in[2];
    const float* W2  = (const float*)d_in[3];
    const float* b2  = (const float*)d_in[4];
    const float* Wfc = (const float*)d_in[5];
    const float* bfc = (const float*)d_in[6];
    float* out = (float*)d_out;

    // workspace layout (16 MiB used)
    char* ws = (char*)d_ws;
    int*   cnt  = (int*)  (ws + 0);                 // 32 KB
    float* s    = (float*)(ws + (32 << 10));        // 32 KB
    float* tt   = (float*)(ws + (64 << 10));        // 32 KB
    float* v    = (float*)(ws + (96 << 10));        // 1 KB
    int*   flag = (int*)  (ws + (100 << 10));       // 4 B
    float* P    = (float*)(ws + (128 << 10));       // 64 KB (64 x 256)
    int*   nbr  = (int*)  (ws + (1 << 20));         // 4 MB
    float* g    = (float*)(ws + (8 << 20));         // 8 MB (slow path only)

    k_scan  <<<N_NODES + 16, 256, 0, stream>>>(adj, W1, b1, W2, cnt, nbr, v, flag);
    k_srow  <<<N_NODES / 4, 256, 0, stream>>>(cnt, nbr, s, tt);
    k_gemm  <<<N_NODES / G_ROWS, 256, 0, stream>>>(s, W1, b1, W2, flag, g);
    k_pool  <<<POOL_BLK, 256, 0, stream>>>(cnt, nbr, s, tt, g, v, b2, flag, P);
    k_finish<<<1, 256, 0, stream>>>(P, Wfc, bfc, out);
}